// Round 11
// baseline (157.488 us; speedup 1.0000x reference)
//
#include <hip/hip_runtime.h>
#include <math.h>

#define NROWS 200000
#define MCOLS 256
#define KINST 200
#define NLAB  201
#define SPLIT 8        // gather blocks per label
#define HBLK  64       // histogram partial blocks
#define PROBE_PASSES 3 // instrumentation: pass 0 real, passes 1-2 into scratch

// ---- ws layout (float/int elements) ----
// [0,16384)        hist64 (int) | [16384..] hist | [16640..] off | [16896..] cursor
// [17152] attrSum [17153] repSum [17154] bgSum [17155] npres
// [17408,217408)   rowidx (int N)
// [217408,268608)  seg (200*256)      <- zeroed by k_hist
// [268608,319808)  seg2 (scratch, probe passes 1-2, never read)
// [319812]         bg2  (scratch)

__device__ __forceinline__ float sigf(float x) {
    return __builtin_amdgcn_rcpf(1.0f + __expf(-x));
}
__device__ __forceinline__ float logsig(float x) {
    return -__logf(1.0f + __expf(-x));
}

__global__ __launch_bounds__(256) void k_hist(const int* __restrict__ labels,
                                              int* __restrict__ hist64,
                                              int* __restrict__ cursor,
                                              float* __restrict__ scalars,
                                              float* __restrict__ seg) {
    const int gt = blockIdx.x * 256 + threadIdx.x;
    for (int e = gt; e < KINST * MCOLS; e += HBLK * 256) seg[e] = 0.0f;
    if (gt < NLAB) cursor[gt] = 0;
    if (gt >= 256 && gt < 260) scalars[gt - 256] = 0.0f;

    __shared__ int lh[NLAB];
    for (int t = threadIdx.x; t < NLAB; t += 256) lh[t] = 0;
    __syncthreads();
    for (int i = gt; i < NROWS; i += HBLK * 256)
        atomicAdd(&lh[labels[i]], 1);
    __syncthreads();
    for (int t = threadIdx.x; t < NLAB; t += 256)
        hist64[t * HBLK + blockIdx.x] = lh[t];
}

__global__ __launch_bounds__(256) void k_scatter(const int* __restrict__ labels,
                                                 const int* __restrict__ hist64,
                                                 int* __restrict__ hist,
                                                 int* __restrict__ off,
                                                 int* __restrict__ cursor,
                                                 int* __restrict__ rowidx) {
    __shared__ int sc[256];
    __shared__ int s_off[NLAB + 1];
    __shared__ int lh[NLAB];
    __shared__ int lbase[NLAB];
    const int t = threadIdx.x;

    int v = 0;
    if (t < NLAB) {
        const int4* p = (const int4*)(hist64 + t * HBLK);
        #pragma unroll
        for (int q = 0; q < HBLK / 4; ++q) {
            const int4 h = p[q];
            v += h.x + h.y + h.z + h.w;
        }
    }
    sc[t] = v;
    __syncthreads();
    for (int d = 1; d < 256; d <<= 1) {
        const int add = (t >= d) ? sc[t - d] : 0;
        __syncthreads();
        sc[t] += add;
        __syncthreads();
    }
    if (t < NLAB) s_off[t] = sc[t] - v;
    if (t == NLAB - 1) s_off[NLAB] = sc[t];
    if (blockIdx.x == 0) {
        if (t < NLAB) { hist[t] = v; off[t] = sc[t] - v; }
        if (t == NLAB - 1) off[NLAB] = sc[t];
    }
    for (int q = t; q < NLAB; q += 256) lh[q] = 0;
    __syncthreads();

    const int chunk = (NROWS + gridDim.x - 1) / gridDim.x;
    const int lo = blockIdx.x * chunk;
    int hi = lo + chunk; if (hi > NROWS) hi = NROWS;
    for (int i = lo + t; i < hi; i += 256) atomicAdd(&lh[labels[i]], 1);
    __syncthreads();
    for (int q = t; q < NLAB; q += 256) {
        const int c = lh[q];
        lbase[q] = c ? (s_off[q] + atomicAdd(&cursor[q], c)) : 0;
        lh[q] = 0;
    }
    __syncthreads();
    for (int i = lo + t; i < hi; i += 256) {
        const int l = labels[i];
        rowidx[lbase[l] + atomicAdd(&lh[l], 1)] = i;
    }
}

// PROBE version of the hot kernel: identical math, run PROBE_PASSES times;
// pass 0 writes real outputs, later passes write scratch (never read).
// Purpose: dispatch lasts ~3x k_main -> appears in rocprof top-5 with counters.
__global__ __launch_bounds__(256, 8) void k_main_probe(const float* __restrict__ x,
                                                       const int* __restrict__ rowidx,
                                                       const int* __restrict__ off,
                                                       float* __restrict__ seg,
                                                       float* __restrict__ bgsum,
                                                       float* __restrict__ seg2,
                                                       float* __restrict__ bg2) {
    const int label = blockIdx.x / SPLIT;
    const int s     = blockIdx.x % SPLIT;
    const int lo = off[label], hi = off[label + 1];
    const int cnt = hi - lo;
    const int per = (cnt + SPLIT - 1) / SPLIT;
    const int a = lo + s * per;
    int b = a + per; if (b > hi) b = hi;
    const int nb = b - a;
    if (nb <= 0) return;
    const int wave = threadIdx.x >> 6, lane = threadIdx.x & 63;

    __shared__ int   idx[512];
    __shared__ float buf[4][256];

    const bool lds_ok = (nb <= 512);
    if (lds_ok) {
        for (int i = threadIdx.x; i < nb; i += 256) idx[i] = rowidx[a + i];
        __syncthreads();
    }
    #define ROWID(r) (lds_ok ? idx[r] : rowidx[a + (r)])

    for (int pass = 0; pass < PROBE_PASSES; ++pass) {
        float* sdst = (pass == 0) ? seg : seg2;
        float* bdst = (pass == 0) ? bgsum : bg2;

        if (label == 0) {
            float acc = 0.0f;
            int r = wave;
            for (; r + 12 < nb; r += 16) {
                const int r0 = ROWID(r), r1 = ROWID(r + 4), r2 = ROWID(r + 8), r3 = ROWID(r + 12);
                const float4 u0 = *(const float4*)(x + (size_t)r0 * MCOLS + lane * 4);
                const float4 u1 = *(const float4*)(x + (size_t)r1 * MCOLS + lane * 4);
                const float4 u2 = *(const float4*)(x + (size_t)r2 * MCOLS + lane * 4);
                const float4 u3 = *(const float4*)(x + (size_t)r3 * MCOLS + lane * 4);
                acc += sigf(u0.x) + sigf(u0.y) + sigf(u0.z) + sigf(u0.w);
                acc += sigf(u1.x) + sigf(u1.y) + sigf(u1.z) + sigf(u1.w);
                acc += sigf(u2.x) + sigf(u2.y) + sigf(u2.z) + sigf(u2.w);
                acc += sigf(u3.x) + sigf(u3.y) + sigf(u3.z) + sigf(u3.w);
            }
            for (; r < nb; r += 4) {
                const int r0 = ROWID(r);
                const float4 u = *(const float4*)(x + (size_t)r0 * MCOLS + lane * 4);
                acc += sigf(u.x) + sigf(u.y) + sigf(u.z) + sigf(u.w);
            }
            for (int o = 32; o > 0; o >>= 1) acc += __shfl_xor(acc, o);
            if (lane == 0) buf[0][wave] = acc;
            __syncthreads();
            if (threadIdx.x == 0)
                atomicAdd(bdst, buf[0][0] + buf[0][1] + buf[0][2] + buf[0][3]);
        } else {
            float a0 = 0.f, a1 = 0.f, a2 = 0.f, a3 = 0.f;
            int r = wave;
            for (; r + 12 < nb; r += 16) {
                const int r0 = ROWID(r), r1 = ROWID(r + 4), r2 = ROWID(r + 8), r3 = ROWID(r + 12);
                const float4 u0 = *(const float4*)(x + (size_t)r0 * MCOLS + lane * 4);
                const float4 u1 = *(const float4*)(x + (size_t)r1 * MCOLS + lane * 4);
                const float4 u2 = *(const float4*)(x + (size_t)r2 * MCOLS + lane * 4);
                const float4 u3 = *(const float4*)(x + (size_t)r3 * MCOLS + lane * 4);
                a0 += logsig(u0.x) + logsig(u1.x) + logsig(u2.x) + logsig(u3.x);
                a1 += logsig(u0.y) + logsig(u1.y) + logsig(u2.y) + logsig(u3.y);
                a2 += logsig(u0.z) + logsig(u1.z) + logsig(u2.z) + logsig(u3.z);
                a3 += logsig(u0.w) + logsig(u1.w) + logsig(u2.w) + logsig(u3.w);
            }
            for (; r < nb; r += 4) {
                const int r0 = ROWID(r);
                const float4 u = *(const float4*)(x + (size_t)r0 * MCOLS + lane * 4);
                a0 += logsig(u.x); a1 += logsig(u.y); a2 += logsig(u.z); a3 += logsig(u.w);
            }
            buf[wave][lane * 4 + 0] = a0;
            buf[wave][lane * 4 + 1] = a1;
            buf[wave][lane * 4 + 2] = a2;
            buf[wave][lane * 4 + 3] = a3;
            __syncthreads();
            const int c = threadIdx.x;
            const float v = buf[0][c] + buf[1][c] + buf[2][c] + buf[3][c];
            atomicAdd(&sdst[(size_t)(label - 1) * MCOLS + c], v);
        }
        __syncthreads();   // buf reuse across passes
    }
    #undef ROWID
}

__global__ __launch_bounds__(256) void k_tail(const float* __restrict__ seg,
                                              const int* __restrict__ hist,
                                              float* __restrict__ attrSum,
                                              float* __restrict__ repSum,
                                              int* __restrict__ npres) {
    const int i = blockIdx.x;
    const int tid = threadIdx.x, wave = tid >> 6, lane = tid & 63;
    __shared__ int   s_hist[NLAB];
    __shared__ float s_red[4];
    for (int t = tid; t < NLAB; t += 256) s_hist[t] = hist[t];
    __syncthreads();
    const int cnt_i = s_hist[i + 1];
    if (cnt_i == 0) return;

    const float4 sgi = *(const float4*)(seg + (size_t)i * MCOLS + lane * 4);
    const float inv = 1.0f / (float)cnt_i;
    const float g0 = sgi.x * inv, g1 = sgi.y * inv, g2 = sgi.z * inv, g3 = sgi.w * inv;
    float4 pi;
    pi.x = __expf(g0); pi.y = __expf(g1); pi.z = __expf(g2); pi.w = __expf(g3);

    if (wave == 0) {
        float m = fmaxf(fmaxf(g0, g1), fmaxf(g2, g3));
        for (int o = 32; o > 0; o >>= 1) m = fmaxf(m, __shfl_xor(m, o));
        float e = __expf(g0 - m) + __expf(g1 - m) + __expf(g2 - m) + __expf(g3 - m);
        for (int o = 32; o > 0; o >>= 1) e += __shfl_xor(e, o);
        if (lane == 0) {
            atomicAdd(attrSum, -(m + __logf(e)));
            atomicAdd(npres, 1);
        }
    }

    float rep = 0.0f;
    for (int j = wave; j < KINST; j += 4) {
        const int cnt_j = s_hist[j + 1];
        if (j == i || cnt_j == 0) continue;
        const float4 sgj = *(const float4*)(seg + (size_t)j * MCOLS + lane * 4);
        const float invj = 1.0f / (float)cnt_j;
        const float dx = pi.x - __expf(sgj.x * invj);
        const float dy = pi.y - __expf(sgj.y * invj);
        const float dz = pi.z - __expf(sgj.z * invj);
        const float dw = pi.w - __expf(sgj.w * invj);
        float sq = dx * dx + dy * dy + dz * dz + dw * dw;
        for (int o = 32; o > 0; o >>= 1) sq += __shfl_xor(sq, o);
        if (lane == 0) rep += fmaxf(1.0f - sqrtf(sq), 0.0f);
    }
    if (lane == 0) s_red[wave] = rep;
    __syncthreads();
    if (tid == 0) atomicAdd(repSum, s_red[0] + s_red[1] + s_red[2] + s_red[3]);
}

__global__ void k_final(const float* __restrict__ attrSum,
                        const int* __restrict__ npres,
                        const float* __restrict__ repSum,
                        const float* __restrict__ bgSum,
                        const int* __restrict__ hist,
                        float* __restrict__ out) {
    if (threadIdx.x == 0 && blockIdx.x == 0) {
        const int npi = *npres;
        const float np = (float)(npi > 0 ? npi : 1);
        const float attractive = *attrSum / np;
        const long long pr = (long long)npi * (npi - 1);
        const float repulsive = *repSum / (float)(pr > 0 ? pr : 1);
        const float bgc = fmaxf((float)hist[0], 1.0f);
        const float bg = *bgSum / (bgc * (float)MCOLS);
        out[0] = attractive + repulsive + bg;
        out[1] = attractive;
        out[2] = repulsive;
        out[3] = bg;
    }
}

extern "C" void kernel_launch(void* const* d_in, const int* in_sizes, int n_in,
                              void* d_out, int out_size, void* d_ws, size_t ws_size,
                              hipStream_t stream) {
    const float* x      = (const float*)d_in[0];
    const int*   labels = (const int*)d_in[1];
    float* out = (float*)d_out;
    float* w   = (float*)d_ws;

    int*   hist64  = (int*)w;
    int*   hist    = (int*)(w + 16384);
    int*   off     = (int*)(w + 16640);
    int*   cursor  = (int*)(w + 16896);
    float* scalars = w + 17152;
    float* attrSum = w + 17152;
    float* repSum  = w + 17153;
    float* bgSum   = w + 17154;
    int*   npres   = (int*)(w + 17155);
    int*   rowidx  = (int*)(w + 17408);
    float* seg     = w + 217408;
    float* seg2    = w + 268608;   // probe scratch, never read
    float* bg2     = w + 319812;   // probe scratch, never read

    k_hist      <<<HBLK, 256, 0, stream>>>(labels, hist64, cursor, scalars, seg);
    k_scatter   <<<256, 256, 0, stream>>>(labels, hist64, hist, off, cursor, rowidx);
    k_main_probe<<<NLAB * SPLIT, 256, 0, stream>>>(x, rowidx, off, seg, bgSum, seg2, bg2);
    k_tail      <<<KINST, 256, 0, stream>>>(seg, hist, attrSum, repSum, npres);
    k_final     <<<1, 64, 0, stream>>>(attrSum, npres, repSum, bgSum, hist, out);
}

// Round 12
// 91.164 us; speedup vs baseline: 1.7275x; 1.7275x over previous
//
#include <hip/hip_runtime.h>
#include <math.h>

#define NROWS 200000
#define MCOLS 256
#define KINST 200
#define NLAB  201
#define SPLIT 8        // gather blocks per label
#define HBLK  64       // histogram partial blocks

// ---- ws layout (float/int elements) ----
// [0,16384)        hist64 (int) | [16384..] hist | [16640..] off | [16896..] cursor
// [17152] attrSum [17153] repSum [17154] bgSum [17155] npres  <- zeroed by k_hist
// [17408,217408)   rowidx (int N)     <- k_scatter
// [217408,268608)  seg (200*256)      <- zeroed by k_hist
//
// R11 probe findings (journal): k_main ~31.5us warm, NOT HBM-bound (L3-warm
// replay same speed), VALUBusy 54% -> transcendental-issue-bound. Everything
// else ~63us (gaps ~4.75us/dispatch). R8/R9: __threadfence costs ~9us - banned.

__device__ __forceinline__ float sigf(float x) {
    return __builtin_amdgcn_rcpf(1.0f + __expf(-x));
}

__global__ __launch_bounds__(256) void k_hist(const int* __restrict__ labels,
                                              int* __restrict__ hist64,
                                              int* __restrict__ cursor,
                                              float* __restrict__ scalars,
                                              float* __restrict__ seg) {
    const int gt = blockIdx.x * 256 + threadIdx.x;
    for (int e = gt; e < KINST * MCOLS; e += HBLK * 256) seg[e] = 0.0f;
    if (gt < NLAB) cursor[gt] = 0;
    if (gt >= 256 && gt < 260) scalars[gt - 256] = 0.0f;

    __shared__ int lh[NLAB];
    for (int t = threadIdx.x; t < NLAB; t += 256) lh[t] = 0;
    __syncthreads();
    for (int i = gt; i < NROWS; i += HBLK * 256)
        atomicAdd(&lh[labels[i]], 1);
    __syncthreads();
    for (int t = threadIdx.x; t < NLAB; t += 256)
        hist64[t * HBLK + blockIdx.x] = lh[t];
}

__global__ __launch_bounds__(256) void k_scatter(const int* __restrict__ labels,
                                                 const int* __restrict__ hist64,
                                                 int* __restrict__ hist,
                                                 int* __restrict__ off,
                                                 int* __restrict__ cursor,
                                                 int* __restrict__ rowidx) {
    __shared__ int sc[256];
    __shared__ int s_off[NLAB + 1];
    __shared__ int lh[NLAB];
    __shared__ int lbase[NLAB];
    const int t = threadIdx.x;

    int v = 0;
    if (t < NLAB) {
        const int4* p = (const int4*)(hist64 + t * HBLK);
        #pragma unroll
        for (int q = 0; q < HBLK / 4; ++q) {
            const int4 h = p[q];
            v += h.x + h.y + h.z + h.w;
        }
    }
    sc[t] = v;
    __syncthreads();
    for (int d = 1; d < 256; d <<= 1) {
        const int add = (t >= d) ? sc[t - d] : 0;
        __syncthreads();
        sc[t] += add;
        __syncthreads();
    }
    if (t < NLAB) s_off[t] = sc[t] - v;
    if (t == NLAB - 1) s_off[NLAB] = sc[t];
    if (blockIdx.x == 0) {
        if (t < NLAB) { hist[t] = v; off[t] = sc[t] - v; }
        if (t == NLAB - 1) off[NLAB] = sc[t];
    }
    for (int q = t; q < NLAB; q += 256) lh[q] = 0;
    __syncthreads();

    const int chunk = (NROWS + gridDim.x - 1) / gridDim.x;
    const int lo = blockIdx.x * chunk;
    int hi = lo + chunk; if (hi > NROWS) hi = NROWS;
    for (int i = lo + t; i < hi; i += 256) atomicAdd(&lh[labels[i]], 1);
    __syncthreads();
    for (int q = t; q < NLAB; q += 256) {
        const int c = lh[q];
        lbase[q] = c ? (s_off[q] + atomicAdd(&cursor[q], c)) : 0;
        lh[q] = 0;
    }
    __syncthreads();
    for (int i = lo + t; i < hi; i += 256) {
        const int l = labels[i];
        rowidx[lbase[l] + atomicAdd(&lh[l], 1)] = i;
    }
}

// Hot kernel. R12: log->product trick. Sum of log(1+e^-x) kept as product
// (mantissa m in [0.5,1) after renorm, integer exponent-sum e). One v_log per
// ~125 elements instead of per element -> per-element trans load halved.
// 32-bit offsets: x is 204.8MB, r0<<8 + lane<<2 fits uint32.
__global__ __launch_bounds__(256, 8) void k_main(const float* __restrict__ x,
                                                 const int* __restrict__ rowidx,
                                                 const int* __restrict__ off,
                                                 float* __restrict__ seg,
                                                 float* __restrict__ bgsum) {
    const int label = blockIdx.x / SPLIT;
    const int s     = blockIdx.x % SPLIT;
    const int lo = off[label], hi = off[label + 1];
    const int cnt = hi - lo;
    const int per = (cnt + SPLIT - 1) / SPLIT;
    const int a = lo + s * per;
    int b = a + per; if (b > hi) b = hi;
    const int nb = b - a;
    if (nb <= 0) return;
    const int wave = threadIdx.x >> 6, lane = threadIdx.x & 63;
    const unsigned lz = (unsigned)lane << 2;

    __shared__ int   idx[512];
    __shared__ float buf[4][256];

    const bool lds_ok = (nb <= 512);
    if (lds_ok) {
        for (int i = threadIdx.x; i < nb; i += 256) idx[i] = rowidx[a + i];
        __syncthreads();
    }
    #define ROWID(r) (lds_ok ? idx[r] : rowidx[a + (r)])
    #define XROW(rr) (const float4*)(x + (((unsigned)(rr) << 8) + lz))

    if (label == 0) {
        float acc = 0.0f;
        int r = wave;
        for (; r + 12 < nb; r += 16) {
            const int r0 = ROWID(r), r1 = ROWID(r + 4), r2 = ROWID(r + 8), r3 = ROWID(r + 12);
            const float4 u0 = *XROW(r0);
            const float4 u1 = *XROW(r1);
            const float4 u2 = *XROW(r2);
            const float4 u3 = *XROW(r3);
            acc += sigf(u0.x) + sigf(u0.y) + sigf(u0.z) + sigf(u0.w);
            acc += sigf(u1.x) + sigf(u1.y) + sigf(u1.z) + sigf(u1.w);
            acc += sigf(u2.x) + sigf(u2.y) + sigf(u2.z) + sigf(u2.w);
            acc += sigf(u3.x) + sigf(u3.y) + sigf(u3.z) + sigf(u3.w);
        }
        for (; r < nb; r += 4) {
            const int r0 = ROWID(r);
            const float4 u = *XROW(r0);
            acc += sigf(u.x) + sigf(u.y) + sigf(u.z) + sigf(u.w);
        }
        for (int o = 32; o > 0; o >>= 1) acc += __shfl_xor(acc, o);
        if (lane == 0) buf[0][wave] = acc;
        __syncthreads();
        if (threadIdx.x == 0)
            atomicAdd(bgsum, buf[0][0] + buf[0][1] + buf[0][2] + buf[0][3]);
    } else {
        // product accumulators: value = m * 2^e ; m in (0, 2^40) between renorms
        float m0 = 1.f, m1 = 1.f, m2 = 1.f, m3 = 1.f;
        float e0 = 0.f, e1 = 0.f, e2 = 0.f, e3 = 0.f;
        int r = wave;
        for (; r + 12 < nb; r += 16) {
            const int r0 = ROWID(r), r1 = ROWID(r + 4), r2 = ROWID(r + 8), r3 = ROWID(r + 12);
            const float4 u0 = *XROW(r0);
            const float4 u1 = *XROW(r1);
            const float4 u2 = *XROW(r2);
            const float4 u3 = *XROW(r3);
            m0 *= (1.0f + __expf(-u0.x)) * (1.0f + __expf(-u1.x));
            m0 *= (1.0f + __expf(-u2.x)) * (1.0f + __expf(-u3.x));
            m1 *= (1.0f + __expf(-u0.y)) * (1.0f + __expf(-u1.y));
            m1 *= (1.0f + __expf(-u2.y)) * (1.0f + __expf(-u3.y));
            m2 *= (1.0f + __expf(-u0.z)) * (1.0f + __expf(-u1.z));
            m2 *= (1.0f + __expf(-u2.z)) * (1.0f + __expf(-u3.z));
            m3 *= (1.0f + __expf(-u0.w)) * (1.0f + __expf(-u1.w));
            m3 *= (1.0f + __expf(-u2.w)) * (1.0f + __expf(-u3.w));
            // renorm: 4 elements/acc/iter <= ~36 bits growth; keep m in [0.5,1)
            int k0, k1, k2, k3;
            m0 = frexpf(m0, &k0); e0 += (float)k0;
            m1 = frexpf(m1, &k1); e1 += (float)k1;
            m2 = frexpf(m2, &k2); e2 += (float)k2;
            m3 = frexpf(m3, &k3); e3 += (float)k3;
        }
        for (; r < nb; r += 4) {   // <=3 tail rows: <=27 bits, no renorm needed
            const int r0 = ROWID(r);
            const float4 u = *XROW(r0);
            m0 *= (1.0f + __expf(-u.x));
            m1 *= (1.0f + __expf(-u.y));
            m2 *= (1.0f + __expf(-u.z));
            m3 *= (1.0f + __expf(-u.w));
        }
        // Sum log(1+e^-x) = e*ln2 + ln(m); we need the NEGATIVE sum.
        const float LN2 = 0.6931471805599453f;
        buf[wave][lane * 4 + 0] = -(e0 * LN2 + __logf(m0));
        buf[wave][lane * 4 + 1] = -(e1 * LN2 + __logf(m1));
        buf[wave][lane * 4 + 2] = -(e2 * LN2 + __logf(m2));
        buf[wave][lane * 4 + 3] = -(e3 * LN2 + __logf(m3));
        __syncthreads();
        const int c = threadIdx.x;
        const float v = buf[0][c] + buf[1][c] + buf[2][c] + buf[3][c];
        atomicAdd(&seg[(size_t)(label - 1) * MCOLS + c], v);
    }
    #undef ROWID
    #undef XROW
}

__global__ __launch_bounds__(256) void k_tail(const float* __restrict__ seg,
                                              const int* __restrict__ hist,
                                              float* __restrict__ attrSum,
                                              float* __restrict__ repSum,
                                              int* __restrict__ npres) {
    const int i = blockIdx.x;
    const int tid = threadIdx.x, wave = tid >> 6, lane = tid & 63;
    __shared__ int   s_hist[NLAB];
    __shared__ float s_red[4];
    for (int t = tid; t < NLAB; t += 256) s_hist[t] = hist[t];
    __syncthreads();
    const int cnt_i = s_hist[i + 1];
    if (cnt_i == 0) return;

    const float4 sgi = *(const float4*)(seg + (size_t)i * MCOLS + lane * 4);
    const float inv = 1.0f / (float)cnt_i;
    const float g0 = sgi.x * inv, g1 = sgi.y * inv, g2 = sgi.z * inv, g3 = sgi.w * inv;
    float4 pi;
    pi.x = __expf(g0); pi.y = __expf(g1); pi.z = __expf(g2); pi.w = __expf(g3);

    if (wave == 0) {
        float m = fmaxf(fmaxf(g0, g1), fmaxf(g2, g3));
        for (int o = 32; o > 0; o >>= 1) m = fmaxf(m, __shfl_xor(m, o));
        float e = __expf(g0 - m) + __expf(g1 - m) + __expf(g2 - m) + __expf(g3 - m);
        for (int o = 32; o > 0; o >>= 1) e += __shfl_xor(e, o);
        if (lane == 0) {
            atomicAdd(attrSum, -(m + __logf(e)));
            atomicAdd(npres, 1);
        }
    }

    float rep = 0.0f;
    for (int j = wave; j < KINST; j += 4) {
        const int cnt_j = s_hist[j + 1];
        if (j == i || cnt_j == 0) continue;
        const float4 sgj = *(const float4*)(seg + (size_t)j * MCOLS + lane * 4);
        const float invj = 1.0f / (float)cnt_j;
        const float dx = pi.x - __expf(sgj.x * invj);
        const float dy = pi.y - __expf(sgj.y * invj);
        const float dz = pi.z - __expf(sgj.z * invj);
        const float dw = pi.w - __expf(sgj.w * invj);
        float sq = dx * dx + dy * dy + dz * dz + dw * dw;
        for (int o = 32; o > 0; o >>= 1) sq += __shfl_xor(sq, o);
        if (lane == 0) rep += fmaxf(1.0f - sqrtf(sq), 0.0f);
    }
    if (lane == 0) s_red[wave] = rep;
    __syncthreads();
    if (tid == 0) atomicAdd(repSum, s_red[0] + s_red[1] + s_red[2] + s_red[3]);
}

__global__ void k_final(const float* __restrict__ attrSum,
                        const int* __restrict__ npres,
                        const float* __restrict__ repSum,
                        const float* __restrict__ bgSum,
                        const int* __restrict__ hist,
                        float* __restrict__ out) {
    if (threadIdx.x == 0 && blockIdx.x == 0) {
        const int npi = *npres;
        const float np = (float)(npi > 0 ? npi : 1);
        const float attractive = *attrSum / np;
        const long long pr = (long long)npi * (npi - 1);
        const float repulsive = *repSum / (float)(pr > 0 ? pr : 1);
        const float bgc = fmaxf((float)hist[0], 1.0f);
        const float bg = *bgSum / (bgc * (float)MCOLS);
        out[0] = attractive + repulsive + bg;
        out[1] = attractive;
        out[2] = repulsive;
        out[3] = bg;
    }
}

extern "C" void kernel_launch(void* const* d_in, const int* in_sizes, int n_in,
                              void* d_out, int out_size, void* d_ws, size_t ws_size,
                              hipStream_t stream) {
    const float* x      = (const float*)d_in[0];
    const int*   labels = (const int*)d_in[1];
    float* out = (float*)d_out;
    float* w   = (float*)d_ws;

    int*   hist64  = (int*)w;
    int*   hist    = (int*)(w + 16384);
    int*   off     = (int*)(w + 16640);
    int*   cursor  = (int*)(w + 16896);
    float* scalars = w + 17152;
    float* attrSum = w + 17152;
    float* repSum  = w + 17153;
    float* bgSum   = w + 17154;
    int*   npres   = (int*)(w + 17155);
    int*   rowidx  = (int*)(w + 17408);
    float* seg     = w + 217408;

    k_hist   <<<HBLK, 256, 0, stream>>>(labels, hist64, cursor, scalars, seg);
    k_scatter<<<256, 256, 0, stream>>>(labels, hist64, hist, off, cursor, rowidx);
    k_main   <<<NLAB * SPLIT, 256, 0, stream>>>(x, rowidx, off, seg, bgSum);
    k_tail   <<<KINST, 256, 0, stream>>>(seg, hist, attrSum, repSum, npres);
    k_final  <<<1, 64, 0, stream>>>(attrSum, npres, repSum, bgSum, hist, out);
}

// Round 13
// 91.025 us; speedup vs baseline: 1.7302x; 1.0015x over previous
//
#include <hip/hip_runtime.h>
#include <math.h>

#define NROWS 200000
#define MCOLS 256
#define KINST 200
#define NLAB  201
#define SPLIT 8        // gather blocks per label
#define HBLK  64       // histogram partial blocks

// ---- ws layout (float/int elements) ----
// [0,16384)        hist64 (int) | [16384..] hist | [16640..] off | [16896..] cursor
// [17408,217408)   rowidx (int N)     <- k_scatter
// [217408,268608)  seg (200*256)      <- zeroed by k_hist
//
// Journal: R11 probe: k_main ~28-31us warm, NOT HBM-bound; rest ~63us is mostly
// per-dispatch launch overhead (~10us each). R8/R9: __threadfence ~9us - banned.
// R13: k_final eliminated via pre-scaled atomics into out[]; out zeroed by k_hist
// every call (harness does not re-poison between graph replays).

__device__ __forceinline__ float sigf(float x) {
    return __builtin_amdgcn_rcpf(1.0f + __expf(-x));
}

__global__ __launch_bounds__(256) void k_hist(const int* __restrict__ labels,
                                              int* __restrict__ hist64,
                                              int* __restrict__ cursor,
                                              float* __restrict__ seg,
                                              float* __restrict__ out) {
    const int gt = blockIdx.x * 256 + threadIdx.x;
    for (int e = gt; e < KINST * MCOLS; e += HBLK * 256) seg[e] = 0.0f;
    if (gt < NLAB) cursor[gt] = 0;
    if (gt < 4) out[gt] = 0.0f;     // out rebuilt by atomics each call

    __shared__ int lh[NLAB];
    for (int t = threadIdx.x; t < NLAB; t += 256) lh[t] = 0;
    __syncthreads();
    for (int i = gt; i < NROWS; i += HBLK * 256)
        atomicAdd(&lh[labels[i]], 1);
    __syncthreads();
    for (int t = threadIdx.x; t < NLAB; t += 256)
        hist64[t * HBLK + blockIdx.x] = lh[t];
}

__global__ __launch_bounds__(256) void k_scatter(const int* __restrict__ labels,
                                                 const int* __restrict__ hist64,
                                                 int* __restrict__ hist,
                                                 int* __restrict__ off,
                                                 int* __restrict__ cursor,
                                                 int* __restrict__ rowidx) {
    __shared__ int sc[256];
    __shared__ int s_off[NLAB + 1];
    __shared__ int lh[NLAB];
    __shared__ int lbase[NLAB];
    const int t = threadIdx.x;

    int v = 0;
    if (t < NLAB) {
        const int4* p = (const int4*)(hist64 + t * HBLK);
        #pragma unroll
        for (int q = 0; q < HBLK / 4; ++q) {
            const int4 h = p[q];
            v += h.x + h.y + h.z + h.w;
        }
    }
    sc[t] = v;
    __syncthreads();
    for (int d = 1; d < 256; d <<= 1) {
        const int add = (t >= d) ? sc[t - d] : 0;
        __syncthreads();
        sc[t] += add;
        __syncthreads();
    }
    if (t < NLAB) s_off[t] = sc[t] - v;
    if (t == NLAB - 1) s_off[NLAB] = sc[t];
    if (blockIdx.x == 0) {
        if (t < NLAB) { hist[t] = v; off[t] = sc[t] - v; }
        if (t == NLAB - 1) off[NLAB] = sc[t];
    }
    for (int q = t; q < NLAB; q += 256) lh[q] = 0;
    __syncthreads();

    const int chunk = (NROWS + gridDim.x - 1) / gridDim.x;
    const int lo = blockIdx.x * chunk;
    int hi = lo + chunk; if (hi > NROWS) hi = NROWS;
    for (int i = lo + t; i < hi; i += 256) atomicAdd(&lh[labels[i]], 1);
    __syncthreads();
    for (int q = t; q < NLAB; q += 256) {
        const int c = lh[q];
        lbase[q] = c ? (s_off[q] + atomicAdd(&cursor[q], c)) : 0;
        lh[q] = 0;
    }
    __syncthreads();
    for (int i = lo + t; i < hi; i += 256) {
        const int l = labels[i];
        rowidx[lbase[l] + atomicAdd(&lh[l], 1)] = i;
    }
}

// Hot kernel: gather rows of one label; log->product accumulation (R12).
// Label-0 blocks add their bg contribution PRE-SCALED directly to out[3]/out[0].
__global__ __launch_bounds__(256, 8) void k_main(const float* __restrict__ x,
                                                 const int* __restrict__ rowidx,
                                                 const int* __restrict__ off,
                                                 float* __restrict__ seg,
                                                 float* __restrict__ out) {
    const int label = blockIdx.x / SPLIT;
    const int s     = blockIdx.x % SPLIT;
    const int lo = off[label], hi = off[label + 1];
    const int cnt = hi - lo;
    const int per = (cnt + SPLIT - 1) / SPLIT;
    const int a = lo + s * per;
    int b = a + per; if (b > hi) b = hi;
    const int nb = b - a;
    if (nb <= 0) return;
    const int wave = threadIdx.x >> 6, lane = threadIdx.x & 63;
    const unsigned lz = (unsigned)lane << 2;

    __shared__ int   idx[512];
    __shared__ float buf[4][256];

    const bool lds_ok = (nb <= 512);
    if (lds_ok) {
        for (int i = threadIdx.x; i < nb; i += 256) idx[i] = rowidx[a + i];
        __syncthreads();
    }
    #define ROWID(r) (lds_ok ? idx[r] : rowidx[a + (r)])
    #define XROW(rr) (const float4*)(x + (((unsigned)(rr) << 8) + lz))

    if (label == 0) {
        float acc = 0.0f;
        int r = wave;
        for (; r + 12 < nb; r += 16) {
            const int r0 = ROWID(r), r1 = ROWID(r + 4), r2 = ROWID(r + 8), r3 = ROWID(r + 12);
            const float4 u0 = *XROW(r0);
            const float4 u1 = *XROW(r1);
            const float4 u2 = *XROW(r2);
            const float4 u3 = *XROW(r3);
            acc += sigf(u0.x) + sigf(u0.y) + sigf(u0.z) + sigf(u0.w);
            acc += sigf(u1.x) + sigf(u1.y) + sigf(u1.z) + sigf(u1.w);
            acc += sigf(u2.x) + sigf(u2.y) + sigf(u2.z) + sigf(u2.w);
            acc += sigf(u3.x) + sigf(u3.y) + sigf(u3.z) + sigf(u3.w);
        }
        for (; r < nb; r += 4) {
            const int r0 = ROWID(r);
            const float4 u = *XROW(r0);
            acc += sigf(u.x) + sigf(u.y) + sigf(u.z) + sigf(u.w);
        }
        for (int o = 32; o > 0; o >>= 1) acc += __shfl_xor(acc, o);
        if (lane == 0) buf[0][wave] = acc;
        __syncthreads();
        if (threadIdx.x == 0) {
            // pre-scaled bg contribution: cnt = total label-0 rows (>0 here)
            const float c = (buf[0][0] + buf[0][1] + buf[0][2] + buf[0][3])
                            / ((float)cnt * (float)MCOLS);
            atomicAdd(&out[3], c);
            atomicAdd(&out[0], c);
        }
    } else {
        float m0 = 1.f, m1 = 1.f, m2 = 1.f, m3 = 1.f;
        float e0 = 0.f, e1 = 0.f, e2 = 0.f, e3 = 0.f;
        int r = wave;
        for (; r + 12 < nb; r += 16) {
            const int r0 = ROWID(r), r1 = ROWID(r + 4), r2 = ROWID(r + 8), r3 = ROWID(r + 12);
            const float4 u0 = *XROW(r0);
            const float4 u1 = *XROW(r1);
            const float4 u2 = *XROW(r2);
            const float4 u3 = *XROW(r3);
            m0 *= (1.0f + __expf(-u0.x)) * (1.0f + __expf(-u1.x));
            m0 *= (1.0f + __expf(-u2.x)) * (1.0f + __expf(-u3.x));
            m1 *= (1.0f + __expf(-u0.y)) * (1.0f + __expf(-u1.y));
            m1 *= (1.0f + __expf(-u2.y)) * (1.0f + __expf(-u3.y));
            m2 *= (1.0f + __expf(-u0.z)) * (1.0f + __expf(-u1.z));
            m2 *= (1.0f + __expf(-u2.z)) * (1.0f + __expf(-u3.z));
            m3 *= (1.0f + __expf(-u0.w)) * (1.0f + __expf(-u1.w));
            m3 *= (1.0f + __expf(-u2.w)) * (1.0f + __expf(-u3.w));
            int k0, k1, k2, k3;
            m0 = frexpf(m0, &k0); e0 += (float)k0;
            m1 = frexpf(m1, &k1); e1 += (float)k1;
            m2 = frexpf(m2, &k2); e2 += (float)k2;
            m3 = frexpf(m3, &k3); e3 += (float)k3;
        }
        for (; r < nb; r += 4) {
            const int r0 = ROWID(r);
            const float4 u = *XROW(r0);
            m0 *= (1.0f + __expf(-u.x));
            m1 *= (1.0f + __expf(-u.y));
            m2 *= (1.0f + __expf(-u.z));
            m3 *= (1.0f + __expf(-u.w));
        }
        const float LN2 = 0.6931471805599453f;
        buf[wave][lane * 4 + 0] = -(e0 * LN2 + __logf(m0));
        buf[wave][lane * 4 + 1] = -(e1 * LN2 + __logf(m1));
        buf[wave][lane * 4 + 2] = -(e2 * LN2 + __logf(m2));
        buf[wave][lane * 4 + 3] = -(e3 * LN2 + __logf(m3));
        __syncthreads();
        const int c = threadIdx.x;
        const float v = buf[0][c] + buf[1][c] + buf[2][c] + buf[3][c];
        atomicAdd(&seg[(size_t)(label - 1) * MCOLS + c], v);
    }
    #undef ROWID
    #undef XROW
}

// fused stats + repulsive + PRE-SCALED epilogue atomics (np/n_pairs computed
// locally from the full hist each block already holds in LDS).
__global__ __launch_bounds__(256) void k_tail(const float* __restrict__ seg,
                                              const int* __restrict__ hist,
                                              float* __restrict__ out) {
    const int i = blockIdx.x;
    const int tid = threadIdx.x, wave = tid >> 6, lane = tid & 63;
    __shared__ int   s_hist[NLAB];
    __shared__ float s_red[4];
    for (int t = tid; t < NLAB; t += 256) s_hist[t] = hist[t];
    __syncthreads();
    const int cnt_i = s_hist[i + 1];
    if (cnt_i == 0) return;

    // local np / n_pairs (identical in every block)
    int np;
    {
        int c = 0;
        for (int q = lane; q < KINST; q += 64) c += (s_hist[q + 1] > 0) ? 1 : 0;
        for (int o = 32; o > 0; o >>= 1) c += __shfl_xor(c, o);
        np = c;                           // full in every lane of every wave
    }
    const float inv_np    = 1.0f / (float)max(np, 1);
    const long long pr    = (long long)np * (np - 1);
    const float inv_pairs = 1.0f / (float)(pr > 0 ? pr : 1);

    const float4 sgi = *(const float4*)(seg + (size_t)i * MCOLS + lane * 4);
    const float inv = 1.0f / (float)cnt_i;
    const float g0 = sgi.x * inv, g1 = sgi.y * inv, g2 = sgi.z * inv, g3 = sgi.w * inv;
    float4 pi;
    pi.x = __expf(g0); pi.y = __expf(g1); pi.z = __expf(g2); pi.w = __expf(g3);

    if (wave == 0) {   // attractive: logsumexp over 256 log_gm values
        float m = fmaxf(fmaxf(g0, g1), fmaxf(g2, g3));
        for (int o = 32; o > 0; o >>= 1) m = fmaxf(m, __shfl_xor(m, o));
        float e = __expf(g0 - m) + __expf(g1 - m) + __expf(g2 - m) + __expf(g3 - m);
        for (int o = 32; o > 0; o >>= 1) e += __shfl_xor(e, o);
        if (lane == 0) {
            const float c = -(m + __logf(e)) * inv_np;
            atomicAdd(&out[1], c);
            atomicAdd(&out[0], c);
        }
    }

    float rep = 0.0f;
    for (int j = wave; j < KINST; j += 4) {
        const int cnt_j = s_hist[j + 1];
        if (j == i || cnt_j == 0) continue;
        const float4 sgj = *(const float4*)(seg + (size_t)j * MCOLS + lane * 4);
        const float invj = 1.0f / (float)cnt_j;
        const float dx = pi.x - __expf(sgj.x * invj);
        const float dy = pi.y - __expf(sgj.y * invj);
        const float dz = pi.z - __expf(sgj.z * invj);
        const float dw = pi.w - __expf(sgj.w * invj);
        float sq = dx * dx + dy * dy + dz * dz + dw * dw;
        for (int o = 32; o > 0; o >>= 1) sq += __shfl_xor(sq, o);
        if (lane == 0) rep += fmaxf(1.0f - sqrtf(sq), 0.0f);
    }
    if (lane == 0) s_red[wave] = rep;
    __syncthreads();
    if (tid == 0) {
        const float c = (s_red[0] + s_red[1] + s_red[2] + s_red[3]) * inv_pairs;
        atomicAdd(&out[2], c);
        atomicAdd(&out[0], c);
    }
}

extern "C" void kernel_launch(void* const* d_in, const int* in_sizes, int n_in,
                              void* d_out, int out_size, void* d_ws, size_t ws_size,
                              hipStream_t stream) {
    const float* x      = (const float*)d_in[0];
    const int*   labels = (const int*)d_in[1];
    float* out = (float*)d_out;
    float* w   = (float*)d_ws;

    int*   hist64  = (int*)w;
    int*   hist    = (int*)(w + 16384);
    int*   off     = (int*)(w + 16640);
    int*   cursor  = (int*)(w + 16896);
    int*   rowidx  = (int*)(w + 17408);
    float* seg     = w + 217408;

    k_hist   <<<HBLK, 256, 0, stream>>>(labels, hist64, cursor, seg, out);
    k_scatter<<<256, 256, 0, stream>>>(labels, hist64, hist, off, cursor, rowidx);
    k_main   <<<NLAB * SPLIT, 256, 0, stream>>>(x, rowidx, off, seg, out);
    k_tail   <<<KINST, 256, 0, stream>>>(seg, hist, out);
}